// Round 8
// baseline (462.918 us; speedup 1.0000x reference)
//
#include <hip/hip_runtime.h>
#include <math.h>

typedef __bf16 bf16;
typedef bf16 bf16x2 __attribute__((ext_vector_type(2)));
typedef bf16 bf16x4 __attribute__((ext_vector_type(4)));
typedef bf16 bf16x8 __attribute__((ext_vector_type(8)));
typedef float f32x4 __attribute__((ext_vector_type(4)));

#define BATCH 65536
#define QD 32
#define HD 512
#define NT 528
#define BM 64
#define BIAS_C 2.0f

// ws layout (bf16): weights packed as [nt][kt] tiles of 16 feats x 32 k = 512 elems (1 KB).
// tile index = nt*(K/32)+kt; elem (fi,ki) at tile*512 + fi*32 + ki.
// A-frag load for a wave: base + tile*512 + l15*32 + quad*8  -> one coalesced 1 KB load.
#define OFF_WIN  0         // W_in^T tiled: 32 nt x 1 kt
#define OFF_WH1  16384
#define OFF_WH2  278528
#define OFF_WOUT 540672
#define OFF_WO   802816    // 33 nt x 16 kt
#define WT_TOTAL 1073152
#define N_TILES  2096      // WT_TOTAL / 512

#define MFMA(a, b, c) __builtin_amdgcn_mfma_f32_16x16x32_bf16((a), (b), (c), 0, 0, 0)

// One 16(fi) x 32(ki) tile per block. Coalesced 64B-segment reads -> LDS transpose
// (row stride 17 floats kills bank conflicts) -> coalesced bf16x2 writes.
__global__ __launch_bounds__(256) void prep_weights(
    const float* __restrict__ W_in, const float* __restrict__ W_h1,
    const float* __restrict__ W_h2, const float* __restrict__ W_out,
    const float* __restrict__ W_o, bf16* __restrict__ wt)
{
    const int bt = blockIdx.x;

    __shared__ float lds[32][17];
    const float* src; int ld, nt, kt;
    if (bt < 32)        { src = W_in;                 nt = bt;     kt = 0;      ld = HD; }
    else if (bt < 544)  { int t = bt - 32;   src = W_h1;  nt = t >> 4; kt = t & 15; ld = HD; }
    else if (bt < 1056) { int t = bt - 544;  src = W_h2;  nt = t >> 4; kt = t & 15; ld = HD; }
    else if (bt < 1568) { int t = bt - 1056; src = W_out; nt = t >> 4; kt = t & 15; ld = HD; }
    else                { int t = bt - 1568; src = W_o;   nt = t >> 4; kt = t & 15; ld = NT; }

    const int s = threadIdx.x * 2;
    {   // read two consecutive fi of one k-row: 64B segments per 8 lanes, coalesced
        int ki = s >> 4, fi = s & 15;
        const float* p = src + (size_t)(kt * 32 + ki) * ld + nt * 16 + fi;
        lds[ki][fi]     = p[0];
        lds[ki][fi + 1] = p[1];
    }
    __syncthreads();
    {   // write two consecutive ki of one fi column: fully coalesced bf16x2 stores
        int fi = s >> 5, ki = s & 31;
        bf16x2 w;
        w[0] = (bf16)lds[ki][fi];
        w[1] = (bf16)lds[ki + 1][fi];
        *(bf16x2*)(wt + (size_t)bt * 512 + s) = w;
    }
}

// x LDS layout: x[m][f], m=batch(0..63), f=feat(0..511), bf16, XOR-swizzled 16B chunks.
__device__ __forceinline__ int xbyte(int m, int f) {
    return m * 1024 + ((((f >> 3)) ^ m) << 4) + ((f & 7) << 1);
}

// L storage (phase 2): per item il (0..15), hi at il*2048, lo at 32768 + il*2048.
// chunk XOR includes (r>>2) and (il&3); intra-chunk byte XOR includes (il>>2):
// the induced k-permutation is identical for both MFMA operands of the same item,
// so M = L L^T is invariant; measured: bank conflicts 9.7M -> 4.8M (round 4).
__device__ __forceinline__ int lbyte(int il, int r, int c) {
    int ch = (c >> 3) ^ (r & 3) ^ ((r >> 2) & 3) ^ (il & 3);
    int by = (c & 7) ^ ((il >> 2) << 1);
    return il * 2048 + r * 64 + (ch << 4) + (by << 1);
}

// tril index p -> (r,c); diag entries p<32 map to (p,p).
// BRANCHLESS (round-7, verified passing): 5-step integer binary search for
// r = max{r : r(r-1)/2 <= t}. Straight-line, ~18 VALU ops, 3 temps -> no
// register-pressure spike with all 64 acc regs live (removed the +45 MB/dispatch
// scratch-spill: WRITE 313.7 -> 279.3 MB, fused 243 -> 222 us).
__device__ __forceinline__ void p2rc(int p, int& r_, int& c_) {
    int t = p - QD;                 // negative for diag entries; search then yields r=0
    int r = 0;
    #pragma unroll
    for (int b = 16; b; b >>= 1) {
        int cand = r + b;           // max accumulated value is 31
        int tri = (int)(((unsigned)(cand * (cand - 1))) >> 1);
        if (tri <= t) r = cand;
    }
    int c = t - (int)(((unsigned)(r * (r - 1))) >> 1);
    if (p < QD) { r_ = p; c_ = p; }
    else        { r_ = r; c_ = c; }
}

// 512 threads = 8 waves; each wave owns a 64-feature slice (4 x 16-feat tiles).
// 64 KB LDS/block -> TWO blocks co-resident per CU (2 independent barrier domains).
// amdgpu_waves_per_eu(4,4): LDS caps occupancy at 4 waves/EU anyway; pinning max=4
// gives the allocator the full 128-reg/wave budget (64 AGPR acc + 64 arch).
// Round-8 single change: s_setprio(1) around the MFMA/consume cluster of each
// K-step (T5). The 2 co-resident blocks drift out of phase -> real role diversity;
// compute-phase waves preempt staging-phase waves on the SIMD scheduler.
__global__ __launch_bounds__(512) __attribute__((amdgpu_waves_per_eu(4, 4)))
void fused_kernel(
    const float* __restrict__ q,
    const float* __restrict__ b_in, const float* __restrict__ b_h1,
    const float* __restrict__ b_h2, const float* __restrict__ b_out,
    const float* __restrict__ b_o,
    const bf16* __restrict__ wt, float* __restrict__ out)
{
    __shared__ __attribute__((aligned(16))) unsigned char smem[65536];
    const int tid  = threadIdx.x;
    const int lane = tid & 63;
    const int wave = tid >> 6;     // 0..7
    const int l15  = lane & 15;
    const int quad = lane >> 4;
    const int blk  = blockIdx.x;

    const f32x4 zf = {0.f, 0.f, 0.f, 0.f};
    f32x4 acc[4][4];               // [feat tile rt][batch tile ct]

    // ===================== GEMM0: x0 = relu(q @ W_in + b_in) =====================
    {
        bf16x8 bfr[4];
        #pragma unroll
        for (int ct = 0; ct < 4; ++ct) {
            const float* qp = q + (size_t)(blk * 64 + ct * 16 + l15) * QD + quad * 8;
            f32x4 lo = *(const f32x4*)qp;
            f32x4 hi = *(const f32x4*)(qp + 4);
            bf16x8 b;
            #pragma unroll
            for (int j = 0; j < 4; ++j) { b[j] = (bf16)lo[j]; b[4 + j] = (bf16)hi[j]; }
            bfr[ct] = b;
        }
        #pragma unroll
        for (int rt = 0; rt < 4; ++rt) {
            bf16x8 a = *(const bf16x8*)(wt + OFF_WIN + (wave * 4 + rt) * 512 + l15 * 32 + quad * 8);
            #pragma unroll
            for (int ct = 0; ct < 4; ++ct)
                acc[rt][ct] = MFMA(a, bfr[ct], zf);
        }
        #pragma unroll
        for (int rt = 0; rt < 4; ++rt) {
            int f0 = wave * 64 + rt * 16 + quad * 4;
            f32x4 bias = *(const f32x4*)(b_in + f0);
            #pragma unroll
            for (int ct = 0; ct < 4; ++ct) {
                int m = ct * 16 + l15;
                bf16x4 w;
                #pragma unroll
                for (int r = 0; r < 4; ++r) {
                    float v = acc[rt][ct][r] + bias[r];
                    v = v > 0.f ? v : 0.f;
                    w[r] = (bf16)v;
                }
                *(bf16x4*)(smem + xbyte(m, f0)) = w;
            }
        }
    }
    __syncthreads();

    // ===================== Hidden layers h1, h2 (residual) and W_out =====================
    const bf16*  WL[3] = { wt + OFF_WH1, wt + OFF_WH2, wt + OFF_WOUT };
    const float* BL[3] = { b_h1, b_h2, b_out };
    #pragma unroll
    for (int L = 0; L < 3; ++L) {
        #pragma unroll
        for (int rt = 0; rt < 4; ++rt)
            #pragma unroll
            for (int ct = 0; ct < 4; ++ct)
                acc[rt][ct] = zf;
        const bf16* W = WL[L];
        #pragma unroll 2
        for (int kk = 0; kk < 16; ++kk) {
            bf16x8 bfr2[4];
            #pragma unroll
            for (int ct = 0; ct < 4; ++ct) {
                int m = ct * 16 + l15;
                bfr2[ct] = *(const bf16x8*)(smem + m * 1024 + (((kk * 4 + quad) ^ m) << 4));
            }
            __builtin_amdgcn_s_setprio(1);
            #pragma unroll
            for (int rt = 0; rt < 4; ++rt) {
                bf16x8 a = *(const bf16x8*)(W + ((wave * 4 + rt) * 16 + kk) * 512 + l15 * 32 + quad * 8);
                #pragma unroll
                for (int ct = 0; ct < 4; ++ct)
                    acc[rt][ct] = MFMA(a, bfr2[ct], acc[rt][ct]);
            }
            __builtin_amdgcn_s_setprio(0);
        }
        __syncthreads();   // all waves done reading x before overwrite
        {
            const float* Bv = BL[L];
            #pragma unroll
            for (int rt = 0; rt < 4; ++rt) {
                int f0 = wave * 64 + rt * 16 + quad * 4;
                f32x4 bias = *(const f32x4*)(Bv + f0);
                #pragma unroll
                for (int ct = 0; ct < 4; ++ct) {
                    int m = ct * 16 + l15;
                    unsigned char* p = smem + xbyte(m, f0);
                    bf16x4 w;
                    if (L < 2) {   // relu + residual
                        bf16x4 old = *(const bf16x4*)p;
                        #pragma unroll
                        for (int r = 0; r < 4; ++r) {
                            float v = acc[rt][ct][r] + bias[r];
                            v = v > 0.f ? v : 0.f;
                            v += (float)old[r];
                            w[r] = (bf16)v;
                        }
                    } else {       // embed: no relu, no residual
                        #pragma unroll
                        for (int r = 0; r < 4; ++r) {
                            float v = acc[rt][ct][r] + bias[r];
                            w[r] = (bf16)v;
                        }
                    }
                    *(bf16x4*)p = w;
                }
            }
        }
        __syncthreads();
    }

    // ===================== L4: L_params^T = W_o^T @ embed^T  (528 feats) =====================
    f32x4 acc_ex = zf;
    #pragma unroll
    for (int rt = 0; rt < 4; ++rt)
        #pragma unroll
        for (int ct = 0; ct < 4; ++ct)
            acc[rt][ct] = zf;
    #pragma unroll 2
    for (int kk = 0; kk < 16; ++kk) {
        bf16x8 bfr2[4];
        #pragma unroll
        for (int ct = 0; ct < 4; ++ct) {
            int m = ct * 16 + l15;
            bfr2[ct] = *(const bf16x8*)(smem + m * 1024 + (((kk * 4 + quad) ^ m) << 4));
        }
        __builtin_amdgcn_s_setprio(1);
        #pragma unroll
        for (int rt = 0; rt < 4; ++rt) {
            bf16x8 a = *(const bf16x8*)(wt + OFF_WO + ((wave * 4 + rt) * 16 + kk) * 512 + l15 * 32 + quad * 8);
            #pragma unroll
            for (int ct = 0; ct < 4; ++ct)
                acc[rt][ct] = MFMA(a, bfr2[ct], acc[rt][ct]);
        }
        // extra feature tile 512..527 (nt=32): waves 4..7 cover batch group ct = wave-4
        if (wave >= 4) {
            bf16x8 aex = *(const bf16x8*)(wt + OFF_WO + (32 * 16 + kk) * 512 + l15 * 32 + quad * 8);
            if (wave == 4) acc_ex = MFMA(aex, bfr2[0], acc_ex);
            else if (wave == 5) acc_ex = MFMA(aex, bfr2[1], acc_ex);
            else if (wave == 6) acc_ex = MFMA(aex, bfr2[2], acc_ex);
            else acc_ex = MFMA(aex, bfr2[3], acc_ex);
        }
        __builtin_amdgcn_s_setprio(0);
    }
    __syncthreads();   // x (embed) dead; reuse smem for L tiles

    // fold b_o (+ diag BIAS) into acc so the bias registers die before phase 2.
    #pragma unroll
    for (int rt = 0; rt < 4; ++rt) {
        f32x4 b = *(const f32x4*)(b_o + wave * 64 + rt * 16 + quad * 4);
        if (rt < 2 && wave == 0) {   // p = rt*16+quad*4+r < 32 iff wave==0 && rt<2
            #pragma unroll
            for (int r = 0; r < 4; ++r) b[r] += BIAS_C;
        }
        #pragma unroll
        for (int ct = 0; ct < 4; ++ct)
            #pragma unroll
            for (int r = 0; r < 4; ++r)
                acc[rt][ct][r] += b[r];
    }
    if (wave >= 4) {
        f32x4 be = *(const f32x4*)(b_o + 512 + quad * 4);
        #pragma unroll
        for (int r = 0; r < 4; ++r) acc_ex[r] += be[r];
    }

    // hoist full phase-2 LDS byte offsets: p = wave*64 + rt*16 + quad*4 + r is
    // g-invariant and il = l15 is fixed per thread -> 16 precomputed ints.
    int loff[4][4];
    #pragma unroll
    for (int rt = 0; rt < 4; ++rt)
        #pragma unroll
        for (int r = 0; r < 4; ++r) {
            int rr, cc;
            p2rc(wave * 64 + rt * 16 + quad * 4 + r, rr, cc);
            loff[rt][r] = lbyte(l15, rr, cc);
        }
    int loffex[4] = {0, 0, 0, 0};
    if (wave >= 4) {
        #pragma unroll
        for (int r = 0; r < 4; ++r) {
            int rr, cc;
            p2rc(512 + quad * 4 + r, rr, cc);
            loffex[r] = lbyte(l15, rr, cc);
        }
    }

    // ===================== Phase 2: build L (hi/lo bf16) and M = L L^T =====================
    {
        unsigned long long* z = (unsigned long long*)smem;
        #pragma unroll
        for (int i = 0; i < 16; ++i) z[tid + 512 * i] = 0ull;
    }
    __syncthreads();

    #pragma unroll
    for (int g = 0; g < 4; ++g) {
        // ---- write L values for items = batch cols g*16 .. g*16+15 (il = l15) ----
        #pragma unroll
        for (int rt = 0; rt < 4; ++rt) {
            #pragma unroll
            for (int r = 0; r < 4; ++r) {
                float v = acc[rt][g][r];
                bf16 hi = (bf16)v;
                bf16 lo = (bf16)(v - (float)hi);
                int off = loff[rt][r];
                *(bf16*)(smem + off) = hi;
                *(bf16*)(smem + 32768 + off) = lo;
            }
        }
        if (wave == 4 + g) {
            #pragma unroll
            for (int r = 0; r < 4; ++r) {
                float v = acc_ex[r];
                bf16 hi = (bf16)v;
                bf16 lo = (bf16)(v - (float)hi);
                int off = loffex[r];
                *(bf16*)(smem + off) = hi;
                *(bf16*)(smem + 32768 + off) = lo;
            }
        }
        __syncthreads();
        // ---- per-item M = L L^T via hi/lo-split MFMA; wave handles items wave, wave+8 ----
        #pragma unroll
        for (int ii = 0; ii < 2; ++ii) {
            const int it = wave + ii * 8;
            bf16x8 Fh[2], Fl[2];
            #pragma unroll
            for (int tl = 0; tl < 2; ++tl) {
                int m = tl * 16 + l15;
                int ch = quad ^ (m & 3) ^ ((m >> 2) & 3) ^ (it & 3);
                int off = it * 2048 + m * 64 + (ch << 4);
                Fh[tl] = *(const bf16x8*)(smem + off);
                Fl[tl] = *(const bf16x8*)(smem + 32768 + off);
            }
            long base = ((long)(blk * 64 + g * 16 + it)) * 1024;
            #pragma unroll
            for (int mt = 0; mt < 2; ++mt) {
                #pragma unroll
                for (int nt = 0; nt < 2; ++nt) {
                    f32x4 mm = MFMA(Fh[mt], Fh[nt], zf);
                    mm = MFMA(Fh[mt], Fl[nt], mm);
                    mm = MFMA(Fl[mt], Fh[nt], mm);
                    #pragma unroll
                    for (int r = 0; r < 4; ++r)
                        out[base + (long)(mt * 16 + quad * 4 + r) * 32 + nt * 16 + l15] = mm[r];
                }
            }
        }
        __syncthreads();   // L region reused by next group
    }
}

extern "C" void kernel_launch(void* const* d_in, const int* in_sizes, int n_in,
                              void* d_out, int out_size, void* d_ws, size_t ws_size,
                              hipStream_t stream)
{
    const float* q     = (const float*)d_in[0];
    const float* W_in  = (const float*)d_in[1];
    const float* b_in  = (const float*)d_in[2];
    const float* W_h1  = (const float*)d_in[3];
    const float* b_h1  = (const float*)d_in[4];
    const float* W_h2  = (const float*)d_in[5];
    const float* b_h2  = (const float*)d_in[6];
    const float* W_out = (const float*)d_in[7];
    const float* b_out = (const float*)d_in[8];
    const float* W_o   = (const float*)d_in[9];
    const float* b_o   = (const float*)d_in[10];
    float* out = (float*)d_out;
    bf16* wt = (bf16*)d_ws;

    prep_weights<<<N_TILES, 256, 0, stream>>>(W_in, W_h1, W_h2, W_out, W_o, wt);
    fused_kernel<<<BATCH / BM, 512, 0, stream>>>(q, b_in, b_h1, b_h2, b_out, b_o, wt, out);
}

// Round 9
// 420.980 us; speedup vs baseline: 1.0996x; 1.0996x over previous
//
#include <hip/hip_runtime.h>
#include <math.h>

typedef __bf16 bf16;
typedef bf16 bf16x2 __attribute__((ext_vector_type(2)));
typedef bf16 bf16x4 __attribute__((ext_vector_type(4)));
typedef bf16 bf16x8 __attribute__((ext_vector_type(8)));
typedef float f32x4 __attribute__((ext_vector_type(4)));

#define BATCH 65536
#define QD 32
#define HD 512
#define NT 528
#define BM 128
#define BIAS_C 2.0f

// ws layout (bf16): weights packed as [nt][kt] tiles of 16 feats x 32 k = 512 elems (1 KB).
// tile index = nt*(K/32)+kt; elem (fi,ki) at tile*512 + fi*32 + ki.
// A-frag load for a wave: base + tile*512 + l15*32 + quad*8  -> one coalesced 1 KB load.
#define OFF_WIN  0         // W_in^T tiled: 32 nt x 1 kt
#define OFF_WH1  16384
#define OFF_WH2  278528
#define OFF_WOUT 540672
#define OFF_WO   802816    // 33 nt x 16 kt
#define WT_TOTAL 1073152
#define N_TILES  2096      // WT_TOTAL / 512

#define MFMA(a, b, c) __builtin_amdgcn_mfma_f32_16x16x32_bf16((a), (b), (c), 0, 0, 0)

// One 16(fi) x 32(ki) tile per block. Coalesced 64B-segment reads -> LDS transpose
// (row stride 17 floats kills bank conflicts) -> coalesced bf16x2 writes.
__global__ __launch_bounds__(256) void prep_weights(
    const float* __restrict__ W_in, const float* __restrict__ W_h1,
    const float* __restrict__ W_h2, const float* __restrict__ W_out,
    const float* __restrict__ W_o, bf16* __restrict__ wt)
{
    const int bt = blockIdx.x;

    __shared__ float lds[32][17];
    const float* src; int ld, nt, kt;
    if (bt < 32)        { src = W_in;                 nt = bt;     kt = 0;      ld = HD; }
    else if (bt < 544)  { int t = bt - 32;   src = W_h1;  nt = t >> 4; kt = t & 15; ld = HD; }
    else if (bt < 1056) { int t = bt - 544;  src = W_h2;  nt = t >> 4; kt = t & 15; ld = HD; }
    else if (bt < 1568) { int t = bt - 1056; src = W_out; nt = t >> 4; kt = t & 15; ld = HD; }
    else                { int t = bt - 1568; src = W_o;   nt = t >> 4; kt = t & 15; ld = NT; }

    const int s = threadIdx.x * 2;
    {   // read two consecutive fi of one k-row: 64B segments per 8 lanes, coalesced
        int ki = s >> 4, fi = s & 15;
        const float* p = src + (size_t)(kt * 32 + ki) * ld + nt * 16 + fi;
        lds[ki][fi]     = p[0];
        lds[ki][fi + 1] = p[1];
    }
    __syncthreads();
    {   // write two consecutive ki of one fi column: fully coalesced bf16x2 stores
        int fi = s >> 5, ki = s & 31;
        bf16x2 w;
        w[0] = (bf16)lds[ki][fi];
        w[1] = (bf16)lds[ki + 1][fi];
        *(bf16x2*)(wt + (size_t)bt * 512 + s) = w;
    }
}

// x LDS layout: x[m][f], m=batch(0..127), f=feat(0..511), bf16, XOR-swizzled 16B chunks.
// (chunk XOR uses m&63: 64 chunks per row, m spans 128 rows.)
__device__ __forceinline__ int xbyte(int m, int f) {
    return m * 1024 + ((((f >> 3)) ^ (m & 63)) << 4) + ((f & 7) << 1);
}

// L storage (phase 2): per item il (0..15), hi at il*2048, lo at 32768 + il*2048.
// chunk XOR includes (r>>2) and (il&3); intra-chunk byte XOR includes (il>>2):
// the induced k-permutation is identical for both MFMA operands of the same item,
// so M = L L^T is invariant; measured: bank conflicts 9.7M -> 4.8M (round 4).
__device__ __forceinline__ int lbyte(int il, int r, int c) {
    int ch = (c >> 3) ^ (r & 3) ^ ((r >> 2) & 3) ^ (il & 3);
    int by = (c & 7) ^ ((il >> 2) << 1);
    return il * 2048 + r * 64 + (ch << 4) + (by << 1);
}

// tril index p -> (r,c); diag entries p<32 map to (p,p).
// BRANCHLESS (round-7, verified passing): 5-step integer binary search for
// r = max{r : r(r-1)/2 <= t}. Straight-line, ~18 VALU ops, 3 temps -> no
// register-pressure spike (removed the +45 MB/dispatch scratch-spill).
__device__ __forceinline__ void p2rc(int p, int& r_, int& c_) {
    int t = p - QD;                 // negative for diag entries; search then yields r=0
    int r = 0;
    #pragma unroll
    for (int b = 16; b; b >>= 1) {
        int cand = r + b;           // max accumulated value is 31
        int tri = (int)(((unsigned)(cand * (cand - 1))) >> 1);
        if (tri <= t) r = cand;
    }
    int c = t - (int)(((unsigned)(r * (r - 1))) >> 1);
    if (p < QD) { r_ = p; c_ = p; }
    else        { r_ = r; c_ = c; }
}

// ROUND-9 RESTRUCTURE: BM=128, 1024 threads = 16 waves, ONE block/CU (128 KB LDS).
// Rationale (R8 arithmetic): the K-loops were per-CU L2-BW-bound on weight
// streaming (64 KB/kk/CU demanded at MFMA pace = 211 B/cyc >> ~100 B/cyc L2),
// and the 2 co-resident BM=64 blocks each read the SAME 512 KB weight tile.
// Doubling batch rows per block halves weight bytes per CU. Same 128-reg/wave
// footprint (acc[2][8] = 64 AGPR), same 16 waves/CU occupancy. No setprio (R8: -5%).
__global__ __launch_bounds__(1024) __attribute__((amdgpu_waves_per_eu(4, 4)))
void fused_kernel(
    const float* __restrict__ q,
    const float* __restrict__ b_in, const float* __restrict__ b_h1,
    const float* __restrict__ b_h2, const float* __restrict__ b_out,
    const float* __restrict__ b_o,
    const bf16* __restrict__ wt, float* __restrict__ out)
{
    __shared__ __attribute__((aligned(16))) unsigned char smem[131072];
    const int tid  = threadIdx.x;
    const int lane = tid & 63;
    const int wave = tid >> 6;     // 0..15
    const int l15  = lane & 15;
    const int quad = lane >> 4;
    const int blk  = blockIdx.x;

    const f32x4 zf = {0.f, 0.f, 0.f, 0.f};
    f32x4 acc[2][8];               // [feat tile rt][batch tile ct]

    // ===================== GEMM0: x0 = relu(q @ W_in + b_in) =====================
    {
        bf16x8 aA[2];
        #pragma unroll
        for (int rt = 0; rt < 2; ++rt)
            aA[rt] = *(const bf16x8*)(wt + OFF_WIN + (wave * 2 + rt) * 512 + l15 * 32 + quad * 8);
        #pragma unroll
        for (int ct = 0; ct < 8; ++ct) {
            const float* qp = q + (size_t)(blk * BM + ct * 16 + l15) * QD + quad * 8;
            f32x4 lo = *(const f32x4*)qp;
            f32x4 hi = *(const f32x4*)(qp + 4);
            bf16x8 b;
            #pragma unroll
            for (int j = 0; j < 4; ++j) { b[j] = (bf16)lo[j]; b[4 + j] = (bf16)hi[j]; }
            #pragma unroll
            for (int rt = 0; rt < 2; ++rt)
                acc[rt][ct] = MFMA(aA[rt], b, zf);
        }
        #pragma unroll
        for (int rt = 0; rt < 2; ++rt) {
            int f0 = wave * 32 + rt * 16 + quad * 4;
            f32x4 bias = *(const f32x4*)(b_in + f0);
            #pragma unroll
            for (int ct = 0; ct < 8; ++ct) {
                int m = ct * 16 + l15;
                bf16x4 w;
                #pragma unroll
                for (int r = 0; r < 4; ++r) {
                    float v = acc[rt][ct][r] + bias[r];
                    v = v > 0.f ? v : 0.f;
                    w[r] = (bf16)v;
                }
                *(bf16x4*)(smem + xbyte(m, f0)) = w;
            }
        }
    }
    __syncthreads();

    // ===================== Hidden layers h1, h2 (residual) and W_out =====================
    const bf16*  WL[3] = { wt + OFF_WH1, wt + OFF_WH2, wt + OFF_WOUT };
    const float* BL[3] = { b_h1, b_h2, b_out };
    #pragma unroll
    for (int L = 0; L < 3; ++L) {
        #pragma unroll
        for (int rt = 0; rt < 2; ++rt)
            #pragma unroll
            for (int ct = 0; ct < 8; ++ct)
                acc[rt][ct] = zf;
        const bf16* W = WL[L];
        #pragma unroll 2
        for (int kk = 0; kk < 16; ++kk) {
            bf16x8 a0 = *(const bf16x8*)(W + ((wave * 2 + 0) * 16 + kk) * 512 + l15 * 32 + quad * 8);
            bf16x8 a1 = *(const bf16x8*)(W + ((wave * 2 + 1) * 16 + kk) * 512 + l15 * 32 + quad * 8);
            #pragma unroll
            for (int ct = 0; ct < 8; ++ct) {
                int m = ct * 16 + l15;
                bf16x8 b = *(const bf16x8*)(smem + m * 1024 + (((kk * 4 + quad) ^ (m & 63)) << 4));
                acc[0][ct] = MFMA(a0, b, acc[0][ct]);
                acc[1][ct] = MFMA(a1, b, acc[1][ct]);
            }
        }
        __syncthreads();   // all waves done reading x before overwrite
        {
            const float* Bv = BL[L];
            #pragma unroll
            for (int rt = 0; rt < 2; ++rt) {
                int f0 = wave * 32 + rt * 16 + quad * 4;
                f32x4 bias = *(const f32x4*)(Bv + f0);
                #pragma unroll
                for (int ct = 0; ct < 8; ++ct) {
                    int m = ct * 16 + l15;
                    unsigned char* p = smem + xbyte(m, f0);
                    bf16x4 w;
                    if (L < 2) {   // relu + residual
                        bf16x4 old = *(const bf16x4*)p;
                        #pragma unroll
                        for (int r = 0; r < 4; ++r) {
                            float v = acc[rt][ct][r] + bias[r];
                            v = v > 0.f ? v : 0.f;
                            v += (float)old[r];
                            w[r] = (bf16)v;
                        }
                    } else {       // embed: no relu, no residual
                        #pragma unroll
                        for (int r = 0; r < 4; ++r) {
                            float v = acc[rt][ct][r] + bias[r];
                            w[r] = (bf16)v;
                        }
                    }
                    *(bf16x4*)p = w;
                }
            }
        }
        __syncthreads();
    }

    // ===================== L4: L_params^T = W_o^T @ embed^T  (528 feats) =====================
    f32x4 acc_ex = zf;
    #pragma unroll
    for (int rt = 0; rt < 2; ++rt)
        #pragma unroll
        for (int ct = 0; ct < 8; ++ct)
            acc[rt][ct] = zf;
    #pragma unroll 2
    for (int kk = 0; kk < 16; ++kk) {
        bf16x8 a0 = *(const bf16x8*)(wt + OFF_WO + ((wave * 2 + 0) * 16 + kk) * 512 + l15 * 32 + quad * 8);
        bf16x8 a1 = *(const bf16x8*)(wt + OFF_WO + ((wave * 2 + 1) * 16 + kk) * 512 + l15 * 32 + quad * 8);
        #pragma unroll
        for (int ct = 0; ct < 8; ++ct) {
            int m = ct * 16 + l15;
            bf16x8 b = *(const bf16x8*)(smem + m * 1024 + (((kk * 4 + quad) ^ (m & 63)) << 4));
            acc[0][ct] = MFMA(a0, b, acc[0][ct]);
            acc[1][ct] = MFMA(a1, b, acc[1][ct]);
        }
        // extra feature tile 512..527 (nt=32): waves 8..15 cover batch group ct = wave-8
        if (wave >= 8) {
            bf16x8 aex = *(const bf16x8*)(wt + OFF_WO + (32 * 16 + kk) * 512 + l15 * 32 + quad * 8);
            int mex = (wave - 8) * 16 + l15;
            bf16x8 bex = *(const bf16x8*)(smem + mex * 1024 + (((kk * 4 + quad) ^ (mex & 63)) << 4));
            acc_ex = MFMA(aex, bex, acc_ex);
        }
    }
    __syncthreads();   // x (embed) dead; reuse smem for L tiles

    // fold b_o (+ diag BIAS) into acc so the bias registers die before phase 2.
    #pragma unroll
    for (int rt = 0; rt < 2; ++rt) {
        f32x4 b = *(const f32x4*)(b_o + wave * 32 + rt * 16 + quad * 4);
        if (wave == 0) {   // p = rt*16+quad*4+r < 32 iff wave==0 (both rt)
            #pragma unroll
            for (int r = 0; r < 4; ++r) b[r] += BIAS_C;
        }
        #pragma unroll
        for (int ct = 0; ct < 8; ++ct)
            #pragma unroll
            for (int r = 0; r < 4; ++r)
                acc[rt][ct][r] += b[r];
    }
    if (wave >= 8) {
        f32x4 be = *(const f32x4*)(b_o + 512 + quad * 4);
        #pragma unroll
        for (int r = 0; r < 4; ++r) acc_ex[r] += be[r];
    }

    // hoist full phase-2 LDS byte offsets: p = wave*32 + rt*16 + quad*4 + r is
    // g-invariant and il = l15 is fixed per thread -> 8 precomputed ints.
    int loff[2][4];
    #pragma unroll
    for (int rt = 0; rt < 2; ++rt)
        #pragma unroll
        for (int r = 0; r < 4; ++r) {
            int rr, cc;
            p2rc(wave * 32 + rt * 16 + quad * 4 + r, rr, cc);
            loff[rt][r] = lbyte(l15, rr, cc);
        }
    int loffex[4] = {0, 0, 0, 0};
    if (wave >= 8) {
        #pragma unroll
        for (int r = 0; r < 4; ++r) {
            int rr, cc;
            p2rc(512 + quad * 4 + r, rr, cc);
            loffex[r] = lbyte(l15, rr, cc);
        }
    }

    // ===================== Phase 2: build L (hi/lo bf16) and M = L L^T =====================
    {   // zero first 64 KB (L region: 16 items x 2 KB hi + 2 KB lo)
        unsigned long long* z = (unsigned long long*)smem;
        #pragma unroll
        for (int i = 0; i < 8; ++i) z[tid + 1024 * i] = 0ull;
    }
    __syncthreads();

    #pragma unroll
    for (int g = 0; g < 8; ++g) {
        // ---- write L values for items = batch cols g*16 .. g*16+15 (il = l15) ----
        #pragma unroll
        for (int rt = 0; rt < 2; ++rt) {
            #pragma unroll
            for (int r = 0; r < 4; ++r) {
                float v = acc[rt][g][r];
                bf16 hi = (bf16)v;
                bf16 lo = (bf16)(v - (float)hi);
                int off = loff[rt][r];
                *(bf16*)(smem + off) = hi;
                *(bf16*)(smem + 32768 + off) = lo;
            }
        }
        if (wave == 8 + g) {
            #pragma unroll
            for (int r = 0; r < 4; ++r) {
                float v = acc_ex[r];
                bf16 hi = (bf16)v;
                bf16 lo = (bf16)(v - (float)hi);
                int off = loffex[r];
                *(bf16*)(smem + off) = hi;
                *(bf16*)(smem + 32768 + off) = lo;
            }
        }
        __syncthreads();
        // ---- per-item M = L L^T via hi/lo-split MFMA; wave handles item it == wave ----
        {
            const int it = wave;
            bf16x8 Fh[2], Fl[2];
            #pragma unroll
            for (int tl = 0; tl < 2; ++tl) {
                int m = tl * 16 + l15;
                int ch = quad ^ (m & 3) ^ ((m >> 2) & 3) ^ (it & 3);
                int off = it * 2048 + m * 64 + (ch << 4);
                Fh[tl] = *(const bf16x8*)(smem + off);
                Fl[tl] = *(const bf16x8*)(smem + 32768 + off);
            }
            long base = ((long)(blk * BM + g * 16 + it)) * 1024;
            #pragma unroll
            for (int mt = 0; mt < 2; ++mt) {
                #pragma unroll
                for (int nt = 0; nt < 2; ++nt) {
                    f32x4 mm = MFMA(Fh[mt], Fh[nt], zf);
                    mm = MFMA(Fh[mt], Fl[nt], mm);
                    mm = MFMA(Fl[mt], Fh[nt], mm);
                    #pragma unroll
                    for (int r = 0; r < 4; ++r)
                        out[base + (long)(mt * 16 + quad * 4 + r) * 32 + nt * 16 + l15] = mm[r];
                }
            }
        }
        __syncthreads();   // L region reused by next group
    }
}

extern "C" void kernel_launch(void* const* d_in, const int* in_sizes, int n_in,
                              void* d_out, int out_size, void* d_ws, size_t ws_size,
                              hipStream_t stream)
{
    const float* q     = (const float*)d_in[0];
    const float* W_in  = (const float*)d_in[1];
    const float* b_in  = (const float*)d_in[2];
    const float* W_h1  = (const float*)d_in[3];
    const float* b_h1  = (const float*)d_in[4];
    const float* W_h2  = (const float*)d_in[5];
    const float* b_h2  = (const float*)d_in[6];
    const float* W_out = (const float*)d_in[7];
    const float* b_out = (const float*)d_in[8];
    const float* W_o   = (const float*)d_in[9];
    const float* b_o   = (const float*)d_in[10];
    float* out = (float*)d_out;
    bf16* wt = (bf16*)d_ws;

    prep_weights<<<N_TILES, 256, 0, stream>>>(W_in, W_h1, W_h2, W_out, W_o, wt);
    fused_kernel<<<BATCH / BM, 1024, 0, stream>>>(q, b_in, b_h1, b_h2, b_out, b_o, wt, out);
}